// Round 1
// baseline (575.213 us; speedup 1.0000x reference)
//
#include <hip/hip_runtime.h>

#define M_DIM 8192
#define N_DIM 4096
#define K_DIM 4096

typedef __attribute__((ext_vector_type(8))) __bf16 bf16x8;
typedef __attribute__((ext_vector_type(4))) __bf16 bf16x4;
typedef __attribute__((ext_vector_type(4))) float floatx4;

// ---------- async global->LDS, 16B per lane (wave-uniform LDS base) ----------
__device__ __forceinline__ void async_copy16(const void* g, void* l) {
    __builtin_amdgcn_global_load_lds(
        (const __attribute__((address_space(1))) void*)g,
        (__attribute__((address_space(3))) void*)l,
        16, 0, 0);
}

// ---------- deterministic reductions (fp64) ----------
__device__ __forceinline__ double wave_reduce_d(double v) {
    #pragma unroll
    for (int o = 32; o > 0; o >>= 1) v += __shfl_down(v, o, 64);
    return v;
}
__device__ __forceinline__ unsigned wave_reduce_u(unsigned v) {
    #pragma unroll
    for (int o = 32; o > 0; o >>= 1) v += __shfl_down(v, o, 64);
    return v;
}

// Pass 1: per-block partial sums of |w|  (1024 blocks x 256 threads)
__global__ __launch_bounds__(256) void k_abs_sum(const float4* __restrict__ w4,
                                                 double* __restrict__ part, int n4) {
    const int tid = threadIdx.x;
    int idx = blockIdx.x * 256 + tid;
    const int stride = gridDim.x * 256;
    double s = 0.0;
    for (int i = idx; i < n4; i += stride) {
        float4 v = w4[i];
        s += (double)fabsf(v.x) + (double)fabsf(v.y) +
             (double)fabsf(v.z) + (double)fabsf(v.w);
    }
    s = wave_reduce_d(s);
    __shared__ double sm[4];
    if ((tid & 63) == 0) sm[tid >> 6] = s;
    __syncthreads();
    if (tid == 0) part[blockIdx.x] = sm[0] + sm[1] + sm[2] + sm[3];
}

// Reduce 1: delta = 0.7*mean|w|, mean|w|
__global__ __launch_bounds__(256) void k_reduce1(const double* __restrict__ part,
                                                 double* __restrict__ scal) {
    const int tid = threadIdx.x;
    double s = 0.0;
    for (int i = tid; i < 1024; i += 256) s += part[i];
    s = wave_reduce_d(s);
    __shared__ double sm[4];
    if ((tid & 63) == 0) sm[tid >> 6] = s;
    __syncthreads();
    if (tid == 0) {
        double total = sm[0] + sm[1] + sm[2] + sm[3];
        double mean = total / (double)((size_t)N_DIM * K_DIM);
        scal[0] = 0.7 * mean;   // delta
        scal[1] = mean;         // fallback mean|w|
    }
}

// Pass 2: quantize to ternary bf16 + partial masked sum / count
__global__ __launch_bounds__(256) void k_quant(const float4* __restrict__ w4,
                                               bf16x4* __restrict__ tern,
                                               const double* __restrict__ scal,
                                               double* __restrict__ pm,
                                               unsigned* __restrict__ pc, int n4) {
    const double delta = scal[0];
    const int tid = threadIdx.x;
    int idx = blockIdx.x * 256 + tid;
    const int stride = gridDim.x * 256;
    double msum = 0.0;
    unsigned cnt = 0;
    for (int i = idx; i < n4; i += stride) {
        float4 v = w4[i];
        float e[4] = {v.x, v.y, v.z, v.w};
        bf16x4 o;
        #pragma unroll
        for (int c = 0; c < 4; ++c) {
            float wv = e[c];
            float t = ((double)wv > delta) ? 1.0f
                    : (((double)wv < -delta) ? -1.0f : 0.0f);
            if (t != 0.0f) { msum += (double)fabsf(wv); cnt++; }
            o[c] = (__bf16)t;
        }
        tern[i] = o;
    }
    msum = wave_reduce_d(msum);
    cnt  = wave_reduce_u(cnt);
    __shared__ double smd[4];
    __shared__ unsigned smu[4];
    if ((tid & 63) == 0) { smd[tid >> 6] = msum; smu[tid >> 6] = cnt; }
    __syncthreads();
    if (tid == 0) {
        pm[blockIdx.x] = smd[0] + smd[1] + smd[2] + smd[3];
        pc[blockIdx.x] = smu[0] + smu[1] + smu[2] + smu[3];
    }
}

// Reduce 2: alpha
__global__ __launch_bounds__(256) void k_reduce2(const double* __restrict__ pm,
                                                 const unsigned* __restrict__ pc,
                                                 double* __restrict__ scal) {
    const int tid = threadIdx.x;
    double s = 0.0; unsigned c = 0;
    for (int i = tid; i < 1024; i += 256) { s += pm[i]; c += pc[i]; }
    s = wave_reduce_d(s);
    c = wave_reduce_u(c);
    __shared__ double smd[4];
    __shared__ unsigned smu[4];
    if ((tid & 63) == 0) { smd[tid >> 6] = s; smu[tid >> 6] = c; }
    __syncthreads();
    if (tid == 0) {
        double ms = smd[0] + smd[1] + smd[2] + smd[3];
        unsigned ct = smu[0] + smu[1] + smu[2] + smu[3];
        scal[2] = (ct > 0) ? (ms / (double)ct) : scal[1];   // alpha
    }
}

// x: fp32 -> bf16 (exact 1 float4 per thread)
__global__ __launch_bounds__(256) void k_cvt_x(const float4* __restrict__ x4,
                                               bf16x4* __restrict__ xb) {
    int i = blockIdx.x * 256 + threadIdx.x;
    float4 v = x4[i];
    bf16x4 o;
    o[0] = (__bf16)v.x; o[1] = (__bf16)v.y; o[2] = (__bf16)v.z; o[3] = (__bf16)v.w;
    xb[i] = o;
}

// ---------- GEMM: C[m][n] = alpha * sum_k A[m][k]*B[n][k] + bias[n] ----------
// m97 structure: 128x128 tile, BK=32, 4 waves (2x2), 4x4 16x16x32 bf16 MFMA each.
__global__ __launch_bounds__(256) void ternary_gemm(
    const __bf16* __restrict__ A,    // M x K (x in bf16)
    const __bf16* __restrict__ B,    // N x K (ternary in bf16)
    const float*  __restrict__ bias, // N
    const double* __restrict__ scal, // [2] = alpha
    float* __restrict__ C)           // M x N
{
    __shared__ __attribute__((aligned(128))) __bf16 As[128 * 32];
    __shared__ __attribute__((aligned(128))) __bf16 Bs[128 * 32];

    const int tid  = threadIdx.x;
    const int wave = tid >> 6;
    const int lane = tid & 63;
    const int quad = lane >> 4;
    const int l16  = lane & 15;
    const int wr = wave >> 1;   // wave row (0..1) -> 64 rows
    const int wc = wave & 1;    // wave col (0..1) -> 64 cols

    const int br = blockIdx.y;  // M tile
    const int bc = blockIdx.x;  // N tile

    // staging: each wave fills 2 chunks of 16 rows x 32 cols per matrix
    const int srow = lane >> 2;       // row within 16-row chunk
    const int scol = (lane & 3) * 8;  // col offset (bf16 elems), 8 per lane = 16B
    const int c0 = wave * 2;

    const __bf16* gA0 = A + (size_t)(br * 128 + c0 * 16 + srow) * K_DIM + scol;
    const __bf16* gA1 = gA0 + 16 * K_DIM;
    const __bf16* gB0 = B + (size_t)(bc * 128 + c0 * 16 + srow) * K_DIM + scol;
    const __bf16* gB1 = gB0 + 16 * K_DIM;
    __bf16* lA0 = &As[c0 * 512];        // wave-uniform LDS base, lane lands at +lane*16B
    __bf16* lA1 = &As[(c0 + 1) * 512];
    __bf16* lB0 = &Bs[c0 * 512];
    __bf16* lB1 = &Bs[(c0 + 1) * 512];

    floatx4 acc[4][4] = {};

    const int a_off = (wr * 64 + l16) * 32 + quad * 8;
    const int b_off = (wc * 64 + l16) * 32 + quad * 8;

    for (int k0 = 0; k0 < K_DIM; k0 += 32) {
        async_copy16(gA0, lA0);
        async_copy16(gA1, lA1);
        async_copy16(gB0, lB0);
        async_copy16(gB1, lB1);
        gA0 += 32; gA1 += 32; gB0 += 32; gB1 += 32;
        __syncthreads();   // drains vmcnt -> LDS tiles ready

        bf16x8 af[4], bfr[4];
        #pragma unroll
        for (int i = 0; i < 4; ++i)
            af[i] = *(const bf16x8*)&As[a_off + i * 16 * 32];
        #pragma unroll
        for (int j = 0; j < 4; ++j)
            bfr[j] = *(const bf16x8*)&Bs[b_off + j * 16 * 32];

        #pragma unroll
        for (int i = 0; i < 4; ++i)
            #pragma unroll
            for (int j = 0; j < 4; ++j)
                acc[i][j] = __builtin_amdgcn_mfma_f32_16x16x32_bf16(
                    af[i], bfr[j], acc[i][j], 0, 0, 0);
        __syncthreads();   // all reads done before next stage overwrites
    }

    const float alpha = (float)scal[2];
    float bv[4];
    #pragma unroll
    for (int j = 0; j < 4; ++j)
        bv[j] = bias[bc * 128 + wc * 64 + j * 16 + l16];

    // C/D layout (16x16x32): col = lane&15, row = quad*4 + reg
    #pragma unroll
    for (int i = 0; i < 4; ++i) {
        const int row0 = br * 128 + wr * 64 + i * 16 + quad * 4;
        #pragma unroll
        for (int j = 0; j < 4; ++j) {
            const int col = bc * 128 + wc * 64 + j * 16 + l16;
            #pragma unroll
            for (int r = 0; r < 4; ++r)
                C[(size_t)(row0 + r) * N_DIM + col] = acc[i][j][r] * alpha + bv[j];
        }
    }
}

extern "C" void kernel_launch(void* const* d_in, const int* in_sizes, int n_in,
                              void* d_out, int out_size, void* d_ws, size_t ws_size,
                              hipStream_t stream) {
    const float* x    = (const float*)d_in[0];  // (8192, 4096) fp32
    const float* w    = (const float*)d_in[1];  // (4096, 4096) fp32
    const float* bias = (const float*)d_in[2];  // (4096,) fp32
    float* out = (float*)d_out;                 // (8192, 4096) fp32

    // workspace layout
    char* ws = (char*)d_ws;
    double*   d_scal = (double*)ws;               // [0]=delta [1]=mean|w| [2]=alpha
    double*   part1  = (double*)(ws + 64);        // 1024 doubles
    double*   pm     = (double*)(ws + 8256);      // 1024 doubles
    unsigned* pc     = (unsigned*)(ws + 16448);   // 1024 uints
    __bf16*   xb     = (__bf16*)(ws + 32768);                                   // 64 MB
    __bf16*   tern   = (__bf16*)(ws + 32768 + (size_t)M_DIM * K_DIM * 2);       // 32 MB

    const int n4w = (N_DIM * K_DIM) / 4;

    k_abs_sum<<<1024, 256, 0, stream>>>((const float4*)w, part1, n4w);
    k_reduce1<<<1, 256, 0, stream>>>(part1, d_scal);
    k_quant<<<1024, 256, 0, stream>>>((const float4*)w, (bf16x4*)tern, d_scal, pm, pc, n4w);
    k_reduce2<<<1, 256, 0, stream>>>(pm, pc, d_scal);
    k_cvt_x<<<(M_DIM * K_DIM) / 4 / 256, 256, 0, stream>>>((const float4*)x, (bf16x4*)xb);

    dim3 grid(N_DIM / 128, M_DIM / 128);  // (32, 64)
    ternary_gemm<<<grid, 256, 0, stream>>>(xb, tern, bias, d_scal, out);
}